// Round 19
// baseline (56.708 us; speedup 1.0000x reference)
//
#include <hip/hip_runtime.h>

// CLAHE: B=32, C=3, H=W=512, GRID=8x8 -> TILE=64x64 (4096 px), NUM_BINS=256,
// CLIP_LIMIT=40 -> clip value = 640.
// d_ws layout: [0, 6.29MB) f32 LUTs (lut_idx = ((b*8+ty)*8+tx)*3 + c).
// R19 = R18 resubmitted (infra failure): DELETE the v8 intermediate.
// k1 = img->luts only (no v8 stores). k2 reads img directly
// (vv = clip(floor(pix*255)) exactly as the reference). Bet: img is
// L3-resident after k1 (107 MB << 256 MB Infinity Cache) -> k2's read side
// served by L3, HBM becomes write-dominated.
// Ledger: R17 = 50.2 (k1 18.4 @ floor w/ v8; k2 31.8 vs 20.8 floor; 3 nulls
// on k2 internals). Cooperative fusion DEAD (R5: 217, R13: 184).

#define NBINS  256
#define TILE   64
#define CH     3
#define HH     512
#define WW     512
#define CLIPV  640
#define PIXELS 4096   // per tile

#define LUTS_FLOATS (32 * 8 * 8 * 3 * NBINS)          // 1,572,864

typedef float f32x4 __attribute__((ext_vector_type(4)));

// ---------------- Kernel 1: stripe histogram + clip + cumsum -> LUT ------------
// One block per (plane, tile-row): 96*8 = 768 blocks. Pure read + 6.3 MB lut
// write: ~107 MB -> ~15us floor.
__global__ __launch_bounds__(256) void clahe_hist_lut_stripe(const float* __restrict__ img,
                                                             float* __restrict__ luts) {
    const int t     = threadIdx.x;
    const int bid   = blockIdx.x;        // = plane*8 + ty
    const int ty    = bid & 7;
    const int plane = bid >> 3;          // b*3 + c
    const int c     = plane % 3;
    const int bb    = plane / 3;

    __shared__ unsigned int hist[8][NBINS];   // 8 KB
    #pragma unroll
    for (int h = 0; h < 8; ++h) hist[h][t] = 0u;
    __syncthreads();

    const size_t base = ((size_t)plane * HH + (size_t)ty * TILE) * WW;  // float offset
    const f32x4* __restrict__ src = reinterpret_cast<const f32x4*>(img + base);

    // stripe = 64 rows * 128 float4 = 8192 float4; 256 threads x 32 iters.
    #pragma unroll 4
    for (int it = 0; it < 32; ++it) {
        const int f = it * 256 + t;          // linear float4 index in stripe
        const f32x4 v = src[f];
        const int tile = (f & 127) >> 4;     // 4 px of a float4 share one tile
        atomicAdd(&hist[tile][min(max((int)floorf(v.x * 256.0f), 0), 255)], 1u);
        atomicAdd(&hist[tile][min(max((int)floorf(v.y * 256.0f), 0), 255)], 1u);
        atomicAdd(&hist[tile][min(max((int)floorf(v.z * 256.0f), 0), 255)], 1u);
        atomicAdd(&hist[tile][min(max((int)floorf(v.w * 256.0f), 0), 255)], 1u);
    }
    __syncthreads();

    // Each of the 4 waves scans 2 histograms (256 bins = 4 chunks of 64).
    const int lane = t & 63;
    const int wid  = t >> 6;

    #pragma unroll
    for (int s = 0; s < 2; ++s) {
        const int h = wid * 2 + s;
        int carry = 0;
        int incl[4];
        #pragma unroll
        for (int ch = 0; ch < 4; ++ch) {
            int v = min((int)hist[h][ch * 64 + lane], CLIPV);
            #pragma unroll
            for (int off = 1; off < 64; off <<= 1) {
                int n = __shfl_up(v, off, 64);
                if (lane >= off) v += n;
            }
            incl[ch] = carry + v;
            carry += __shfl(v, 63, 64);      // chunk total from lane 63
        }
        const int total    = carry;
        const int excess   = PIXELS - total;           // >= 0
        const int residual = excess & 255;
        const int redist   = excess >> 8;
        const int job = ((bb * 8 + ty) * 8 + h) * 3 + c;
        float* __restrict__ dst = luts + (size_t)job * NBINS;
        #pragma unroll
        for (int ch = 0; ch < 4; ++ch) {
            const int bin = ch * 64 + lane;
            // inclusive cumsum of (clipped + redist + (bin<residual ? 1 : 0));
            // (nb-1)/pixels = 255/4096 exact in fp32; product <= 255 exact.
            const int cum = incl[ch] + redist * (bin + 1) + min(bin + 1, residual);
            dst[bin] = floorf(fminf((float)cum * (255.0f / 4096.0f), 255.0f));
        }
    }
}

// ---------------- Kernel 2: bilinear LUT application (img-direct, 512 thr) -----
// One block = 32-row band of one (b,c) plane (all rows share ty0/ty1; band
// breakpoints 32+64k, 480 are multiples of 32).
// Pack[tx][v] = L1[tx] | L1[tx+1]<<8 | L0[tx]<<16 | L0[tx+1]<<24 (exact ints).
// Entry 7 dups (L7,L7); entry 8 dups col0 for the left edge (wx-invariant).
// Reads img f32 directly (L3-resident after k1); vv = clip(floor(pix*255)).
// fi = it*512 + t keeps wave stores 1KB contiguous; x-geometry thread-constant.
__global__ __launch_bounds__(512) void clahe_apply_band(const float* __restrict__ img,
                                                        const float* __restrict__ luts,
                                                        float* __restrict__ out) {
    __shared__ unsigned int Pack[9][NBINS];   // 9 KB

    const int t     = threadIdx.x;            // 0..511
    const int bid   = blockIdx.x;
    const int g     = bid & 15;               // 32-row band 0..15
    const int plane = bid >> 4;               // b*3 + c, 0..95
    const int c     = plane % 3;
    const int bb    = plane / 3;
    const int y0    = g * 32;

    int ty0, ty1;
    if (y0 < 32)        { ty0 = 0; ty1 = 0; }
    else if (y0 >= 480) { ty0 = 7; ty1 = 7; }
    else                { ty0 = (y0 - 32) >> 6; ty1 = ty0 + 1; }

    const int rb0 = (bb * 8 + ty0) * 8;
    const int rb1 = (bb * 8 + ty1) * 8;

    // Staging: half h (= t>>8) covers tx 4h..4h+3; loads tx 4h..4h+4 (clamp 7).
    const int tt   = t & 255;                 // v index
    const int half = t >> 8;                  // 0 or 1
    int iL0[5], iL1[5];
    #pragma unroll
    for (int j = 0; j < 5; ++j) {
        const int txc = min(half * 4 + j, 7);
        iL0[j] = (int)luts[((size_t)((rb0 + txc) * 3 + c)) * NBINS + tt];
        iL1[j] = (int)luts[((size_t)((rb1 + txc) * 3 + c)) * NBINS + tt];
    }
    #pragma unroll
    for (int j = 0; j < 4; ++j) {
        const int tx = half * 4 + j;
        Pack[tx][tt] = (unsigned)(iL1[j] | (iL1[j + 1] << 8) |
                                  (iL0[j] << 16) | (iL0[j + 1] << 24));
    }
    if (half == 0)
        Pack[8][tt] = (unsigned)(iL1[0] | (iL1[0] << 8) | (iL0[0] << 16) | (iL0[0] << 24));
    __syncthreads();

    // Thread-constant x geometry: this thread always covers pixels x..x+3.
    const int x4f = t & 127;              // float4 column 0..127 (512 ≡ 0 mod 128)
    const int x   = x4f * 4;
    const int tx_sel = (x < 32) ? 8 : ((x >= 480) ? 7 : ((x - 32) >> 6));
    const unsigned int* __restrict__ Row = &Pack[tx_sel][0];
    float wxv[4];
    #pragma unroll
    for (int i = 0; i < 4; ++i) {
        const int xx = x + i;
        wxv[i] = (xx < 32 || xx >= 480) ? 1.0f
               : (float)(63 - ((xx - 32) & 63)) * (1.0f / 63.0f);
    }

    const size_t pb = (((size_t)plane) << 18) + (size_t)y0 * WW;   // float offset
    const f32x4* __restrict__ imgw = reinterpret_cast<const f32x4*>(img + pb);
    f32x4* __restrict__ outw = reinterpret_cast<f32x4*>(out + pb);

    // band = 32 rows * 128 float4 = 4096 float4; 8 iters x 512 threads.
    #pragma unroll 4
    for (int it = 0; it < 8; ++it) {
        const int fi  = it * 512 + t;     // lane-consecutive float4 index
        const int row = fi >> 7;          // = it*4 + (t>>7)
        const int y   = y0 + row;
        // On edge bands L0==L1 -> slope 0 -> wy's value irrelevant; safe.
        const float wy = (float)(63 - ((y - 32) & 63)) * (1.0f / 63.0f);

        const f32x4 f = imgw[fi];
        float pix[4] = {f.x, f.y, f.z, f.w};

        f32x4 res;
        #pragma unroll
        for (int i = 0; i < 4; ++i) {
            const int vv = min(max((int)floorf(pix[i] * 255.0f), 0), 255);
            const unsigned int raw = Row[vv];
            const float l1a = (float)(raw & 255u);           // v_cvt_f32_ubyte0
            const float l1b = (float)((raw >> 8) & 255u);    // v_cvt_f32_ubyte1
            const float l0a = (float)((raw >> 16) & 255u);   // v_cvt_f32_ubyte2
            const float l0b = (float)(raw >> 24);            // v_cvt_f32_ubyte3
            const float r0 = fmaf(wy, l0a - l1a, l1a);       // col tx0 value
            const float r1 = fmaf(wy, l0b - l1b, l1b);       // col tx1 value
            res[i] = fmaf(wxv[i], r0 - r1, r1) * (1.0f / 255.0f);
        }
        outw[fi] = res;
    }
}

extern "C" void kernel_launch(void* const* d_in, const int* in_sizes, int n_in,
                              void* d_out, int out_size, void* d_ws, size_t ws_size,
                              hipStream_t stream) {
    const float* img  = (const float*)d_in[0];
    float*       out  = (float*)d_out;
    float*       luts = (float*)d_ws;

    // Kernel 1: one block per (plane, tile-row) stripe: 96*8 = 768 blocks
    clahe_hist_lut_stripe<<<768, 256, 0, stream>>>(img, luts);
    // Kernel 2: one block per (plane, 32-row band): 96*16 = 1536 blocks x 512
    clahe_apply_band<<<1536, 512, 0, stream>>>(img, luts, out);
}

// Round 20
// 48.810 us; speedup vs baseline: 1.1618x; 1.1618x over previous
//
#include <hip/hip_runtime.h>

// CLAHE: B=32, C=3, H=W=512, GRID=8x8 -> TILE=64x64 (4096 px), NUM_BINS=256,
// CLIP_LIMIT=40 -> clip value = 640.
// d_ws layout: [0, 6.29MB) f32 LUTs (lut_idx = ((b*8+ty)*8+tx)*3 + c),
//              [6.29MB, +25.2MB) u8 quantized image v = clip(floor(img*255)).
// R20 = R17 (50.2us best: v8 + 512-thread k2) + two L2-locality changes:
//  (a) XCD-aligned k2 block remap: block applying band g of plane p gets
//      bid%8 == (g>>1)%8 == the XCD slot of the k1 stripe that WROTE its v8
//      (round-robin dispatch assumption; perf-only).
//  (b) nontemporal store for `out` (never re-read; don't evict v8/luts from L2).
//      NT LOADS stay off (R9 regression was NT loads forcing HBM reads).
// Ledger: k1 18.4 @ 132MB floor (7.2 TB/s); k2 31.8 @ 131MB = 4.0 TB/s with
// FETCH 22MB (L2 misses on v8 = cross-XCD). R19 falsified no-v8 (56.7).
// Cooperative fusion DEAD (R5: 217, R13: 184).

#define NBINS  256
#define TILE   64
#define CH     3
#define HH     512
#define WW     512
#define CLIPV  640
#define PIXELS 4096   // per tile

#define LUTS_FLOATS (32 * 8 * 8 * 3 * NBINS)          // 1,572,864
#define V8_BYTES    ((size_t)32 * 3 * HH * WW)        // 25,165,824

typedef float f32x4 __attribute__((ext_vector_type(4)));

// ---------------- Kernel 1: stripe histogram + clip + cumsum -> LUT ------------
// One block per (plane, tile-row): 96*8 = 768 blocks. At combined-BW floor.
__global__ __launch_bounds__(256) void clahe_hist_lut_stripe(const float* __restrict__ img,
                                                             float* __restrict__ luts,
                                                             unsigned char* __restrict__ v8,
                                                             int write_v8) {
    const int t     = threadIdx.x;
    const int bid   = blockIdx.x;        // = plane*8 + ty  (XCD slot = ty%8 = ty)
    const int ty    = bid & 7;
    const int plane = bid >> 3;          // b*3 + c
    const int c     = plane % 3;
    const int bb    = plane / 3;

    __shared__ unsigned int hist[8][NBINS];   // 8 KB
    #pragma unroll
    for (int h = 0; h < 8; ++h) hist[h][t] = 0u;
    __syncthreads();

    const size_t base = ((size_t)plane * HH + (size_t)ty * TILE) * WW;  // float offset
    const f32x4* __restrict__ src  = reinterpret_cast<const f32x4*>(img + base);
    uchar4*      __restrict__ dst8 = reinterpret_cast<uchar4*>(v8 + base);

    // stripe = 64 rows * 128 float4 = 8192 float4; 256 threads x 32 iters.
    #pragma unroll 4
    for (int it = 0; it < 32; ++it) {
        const int f = it * 256 + t;          // linear float4 index in stripe
        const f32x4 v = src[f];
        const int tile = (f & 127) >> 4;     // 4 px of a float4 share one tile
        atomicAdd(&hist[tile][min(max((int)floorf(v.x * 256.0f), 0), 255)], 1u);
        atomicAdd(&hist[tile][min(max((int)floorf(v.y * 256.0f), 0), 255)], 1u);
        atomicAdd(&hist[tile][min(max((int)floorf(v.z * 256.0f), 0), 255)], 1u);
        atomicAdd(&hist[tile][min(max((int)floorf(v.w * 256.0f), 0), 255)], 1u);
        if (write_v8) {
            uchar4 q;
            q.x = (unsigned char)min(max((int)floorf(v.x * 255.0f), 0), 255);
            q.y = (unsigned char)min(max((int)floorf(v.y * 255.0f), 0), 255);
            q.z = (unsigned char)min(max((int)floorf(v.z * 255.0f), 0), 255);
            q.w = (unsigned char)min(max((int)floorf(v.w * 255.0f), 0), 255);
            dst8[f] = q;
        }
    }
    __syncthreads();

    // Each of the 4 waves scans 2 histograms (256 bins = 4 chunks of 64).
    const int lane = t & 63;
    const int wid  = t >> 6;

    #pragma unroll
    for (int s = 0; s < 2; ++s) {
        const int h = wid * 2 + s;
        int carry = 0;
        int incl[4];
        #pragma unroll
        for (int ch = 0; ch < 4; ++ch) {
            int v = min((int)hist[h][ch * 64 + lane], CLIPV);
            #pragma unroll
            for (int off = 1; off < 64; off <<= 1) {
                int n = __shfl_up(v, off, 64);
                if (lane >= off) v += n;
            }
            incl[ch] = carry + v;
            carry += __shfl(v, 63, 64);      // chunk total from lane 63
        }
        const int total    = carry;
        const int excess   = PIXELS - total;           // >= 0
        const int residual = excess & 255;
        const int redist   = excess >> 8;
        const int job = ((bb * 8 + ty) * 8 + h) * 3 + c;
        float* __restrict__ dst = luts + (size_t)job * NBINS;
        #pragma unroll
        for (int ch = 0; ch < 4; ++ch) {
            const int bin = ch * 64 + lane;
            // inclusive cumsum of (clipped + redist + (bin<residual ? 1 : 0));
            // (nb-1)/pixels = 255/4096 exact in fp32; product <= 255 exact.
            const int cum = incl[ch] + redist * (bin + 1) + min(bin + 1, residual);
            dst[bin] = floorf(fminf((float)cum * (255.0f / 4096.0f), 255.0f));
        }
    }
}

// ---------------- Kernel 2: bilinear LUT application (XCD-aligned, NT store) ---
// One block = 32-row band of one (b,c) plane. Block remap: xcd = bid&7 picks
// the band pair {2*xcd, 2*xcd+1}; idx = bid>>3 -> plane = idx>>1, which = idx&1,
// g = 2*xcd + which. Then bid%8 == (g>>1)%8 == ty of the k1 stripe that wrote
// this band's v8 -> same-XCD L2 read-back (round-robin dispatch assumption).
// Pack[tx][v] = L1[tx] | L1[tx+1]<<8 | L0[tx]<<16 | L0[tx+1]<<24 (exact ints).
// Entry 7 dups (L7,L7); entry 8 dups col0 for the left edge (wx-invariant).
// 512 threads; staging split across halves; fi = it*512 + t -> 1KB contiguous
// wave stores; x-geometry thread-constant. `out` stored nontemporally.
template<bool USE_V8>
__global__ __launch_bounds__(512) void clahe_apply_band(const float* __restrict__ img,
                                                        const unsigned char* __restrict__ v8,
                                                        const float* __restrict__ luts,
                                                        float* __restrict__ out) {
    __shared__ unsigned int Pack[9][NBINS];   // 9 KB

    const int t     = threadIdx.x;            // 0..511
    const int bid   = blockIdx.x;
    const int xcd   = bid & 7;                // target XCD slot
    const int idx   = bid >> 3;               // 0..191
    const int plane = idx >> 1;               // b*3 + c, 0..95
    const int g     = 2 * xcd + (idx & 1);    // 32-row band 0..15
    const int c     = plane % 3;
    const int bb    = plane / 3;
    const int y0    = g * 32;

    int ty0, ty1;
    if (y0 < 32)        { ty0 = 0; ty1 = 0; }
    else if (y0 >= 480) { ty0 = 7; ty1 = 7; }
    else                { ty0 = (y0 - 32) >> 6; ty1 = ty0 + 1; }

    const int rb0 = (bb * 8 + ty0) * 8;
    const int rb1 = (bb * 8 + ty1) * 8;

    // Staging: half h (= t>>8) covers tx 4h..4h+3; loads tx 4h..4h+4 (clamp 7).
    const int tt   = t & 255;                 // v index
    const int half = t >> 8;                  // 0 or 1
    int iL0[5], iL1[5];
    #pragma unroll
    for (int j = 0; j < 5; ++j) {
        const int txc = min(half * 4 + j, 7);
        iL0[j] = (int)luts[((size_t)((rb0 + txc) * 3 + c)) * NBINS + tt];
        iL1[j] = (int)luts[((size_t)((rb1 + txc) * 3 + c)) * NBINS + tt];
    }
    #pragma unroll
    for (int j = 0; j < 4; ++j) {
        const int tx = half * 4 + j;
        Pack[tx][tt] = (unsigned)(iL1[j] | (iL1[j + 1] << 8) |
                                  (iL0[j] << 16) | (iL0[j + 1] << 24));
    }
    if (half == 0)
        Pack[8][tt] = (unsigned)(iL1[0] | (iL1[0] << 8) | (iL0[0] << 16) | (iL0[0] << 24));
    __syncthreads();

    // Thread-constant x geometry: this thread always covers pixels x..x+3.
    const int x4f = t & 127;              // float4 column 0..127 (512 ≡ 0 mod 128)
    const int x   = x4f * 4;
    const int tx_sel = (x < 32) ? 8 : ((x >= 480) ? 7 : ((x - 32) >> 6));
    const unsigned int* __restrict__ Row = &Pack[tx_sel][0];
    float wxv[4];
    #pragma unroll
    for (int i = 0; i < 4; ++i) {
        const int xx = x + i;
        wxv[i] = (xx < 32 || xx >= 480) ? 1.0f
               : (float)(63 - ((xx - 32) & 63)) * (1.0f / 63.0f);
    }

    const size_t pb = (((size_t)plane) << 18) + (size_t)y0 * WW;   // float offset
    const unsigned int* __restrict__ v8w = reinterpret_cast<const unsigned int*>(v8 + pb);
    const f32x4* __restrict__ imgw = reinterpret_cast<const f32x4*>(img + pb);
    f32x4* __restrict__ outw = reinterpret_cast<f32x4*>(out + pb);

    // band = 32 rows * 128 float4 = 4096 float4; 8 iters x 512 threads.
    #pragma unroll 4
    for (int it = 0; it < 8; ++it) {
        const int fi  = it * 512 + t;     // lane-consecutive float4 index
        const int row = fi >> 7;          // = it*4 + (t>>7)
        const int y   = y0 + row;
        // On edge bands L0==L1 -> slope 0 -> wy's value irrelevant; safe.
        const float wy = (float)(63 - ((y - 32) & 63)) * (1.0f / 63.0f);

        unsigned int w;
        float pix[4];
        if constexpr (USE_V8) {
            w = v8w[fi];
        } else {
            f32x4 f = imgw[fi];
            pix[0] = f.x; pix[1] = f.y; pix[2] = f.z; pix[3] = f.w;
        }

        f32x4 res;
        #pragma unroll
        for (int i = 0; i < 4; ++i) {
            int vv;
            if constexpr (USE_V8) vv = (w >> (8 * i)) & 255;
            else                  vv = min(max((int)floorf(pix[i] * 255.0f), 0), 255);
            const unsigned int raw = Row[vv];
            const float l1a = (float)(raw & 255u);           // v_cvt_f32_ubyte0
            const float l1b = (float)((raw >> 8) & 255u);    // v_cvt_f32_ubyte1
            const float l0a = (float)((raw >> 16) & 255u);   // v_cvt_f32_ubyte2
            const float l0b = (float)(raw >> 24);            // v_cvt_f32_ubyte3
            const float r0 = fmaf(wy, l0a - l1a, l1a);       // col tx0 value
            const float r1 = fmaf(wy, l0b - l1b, l1b);       // col tx1 value
            res[i] = fmaf(wxv[i], r0 - r1, r1) * (1.0f / 255.0f);
        }
        __builtin_nontemporal_store(res, &outw[fi]);   // out never re-read
    }
}

extern "C" void kernel_launch(void* const* d_in, const int* in_sizes, int n_in,
                              void* d_out, int out_size, void* d_ws, size_t ws_size,
                              hipStream_t stream) {
    const float* img  = (const float*)d_in[0];
    float*       out  = (float*)d_out;
    float*       luts = (float*)d_ws;
    unsigned char* v8 = (unsigned char*)d_ws + (size_t)LUTS_FLOATS * 4;

    const bool use_v8 = ws_size >= (size_t)LUTS_FLOATS * 4 + V8_BYTES;

    // Kernel 1: one block per (plane, tile-row) stripe: 96*8 = 768 blocks
    clahe_hist_lut_stripe<<<768, 256, 0, stream>>>(img, luts, v8, use_v8 ? 1 : 0);
    // Kernel 2: one block per (plane, 32-row band), XCD-aligned remap:
    // 96*16 = 1536 blocks x 512 threads
    if (use_v8)
        clahe_apply_band<true><<<1536, 512, 0, stream>>>(img, v8, luts, out);
    else
        clahe_apply_band<false><<<1536, 512, 0, stream>>>(img, v8, luts, out);
}